// Round 7
// baseline (478.096 us; speedup 1.0000x reference)
//
#include <hip/hip_runtime.h>
#include <math.h>

// ---------------------------------------------------------------------------
// R7: conv_mfma re-tiled 8x16 px, 1024 blocks (4/CU, 3 resident; was 512=2/CU
// latency-bound at 30% MfmaUtil), LDS 25.9KB single half-buffer. SE mean fused
// into conv epilogue (shuffle reduce + atomicAdd) — mean_nhwc deleted.
// ---------------------------------------------------------------------------

typedef __attribute__((ext_vector_type(8))) short bf16x8;
typedef __attribute__((ext_vector_type(4))) float f32x4;

__device__ inline float bf2f(unsigned short u) {
    unsigned v = ((unsigned)u) << 16;
    return __builtin_bit_cast(float, v);
}
__device__ inline unsigned short f2bf(float f) {
    unsigned u = __builtin_bit_cast(unsigned, f);
    u += 0x7FFF + ((u >> 16) & 1);   // RNE
    return (unsigned short)(u >> 16);
}

// ---------------- head conv: fp32 NCHW (Cin=3) -> NHWC bf16 (C=128) ---------
__global__ __launch_bounds__(256) void head_conv(
    const float* __restrict__ x, const float* __restrict__ w,
    const float* __restrict__ bias, unsigned short* __restrict__ out)
{
    __shared__ float wlds[216];          // [ci][tap][co8]
    __shared__ float tile[3][34 * 34];
    const int tid = threadIdx.x, cog = blockIdx.y, b = blockIdx.z;
    const int tile_y = (blockIdx.x >> 2) * 32, tile_x = (blockIdx.x & 3) * 32;

    if (tid < 216) {
        int co = tid & 7, rest = tid >> 3, tap = rest % 9, ci = rest / 9;
        wlds[tid] = w[((cog * 8 + co) * 3 + ci) * 9 + tap];
    }
    for (int idx = tid; idx < 3 * 34 * 34; idx += 256) {
        int ci = idx / 1156, rem = idx - ci * 1156;
        int r = rem / 34, c = rem - r * 34;
        int gy = tile_y - 1 + r, gx = tile_x - 1 + c;
        float v = 0.f;
        if ((unsigned)gy < 128u && (unsigned)gx < 128u)
            v = x[(((size_t)(b * 3 + ci)) << 14) + (gy << 7) + gx];
        tile[ci][rem] = v;
    }
    __syncthreads();

    const int ty = tid >> 4, tx = tid & 15, py = ty * 2;
    float acc[2][2][8];
    #pragma unroll
    for (int r = 0; r < 2; ++r)
        #pragma unroll
        for (int h = 0; h < 2; ++h)
            #pragma unroll
            for (int co = 0; co < 8; ++co) acc[r][h][co] = 0.f;

    #pragma unroll
    for (int ci = 0; ci < 3; ++ci) {
        #pragma unroll
        for (int ky = 0; ky < 3; ++ky) {
            #pragma unroll
            for (int kx = 0; kx < 3; ++kx) {
                const float* wp = wlds + (ci * 9 + ky * 3 + kx) * 8;
                float i00 = tile[ci][(py + ky) * 34 + tx + kx];
                float i01 = tile[ci][(py + ky) * 34 + tx + 16 + kx];
                float i10 = tile[ci][(py + 1 + ky) * 34 + tx + kx];
                float i11 = tile[ci][(py + 1 + ky) * 34 + tx + 16 + kx];
                #pragma unroll
                for (int co = 0; co < 8; ++co) {
                    float wv = wp[co];
                    acc[0][0][co] += i00 * wv;
                    acc[0][1][co] += i01 * wv;
                    acc[1][0][co] += i10 * wv;
                    acc[1][1][co] += i11 * wv;
                }
            }
        }
    }

    #pragma unroll
    for (int r = 0; r < 2; ++r) {
        #pragma unroll
        for (int h = 0; h < 2; ++h) {
            int gy = tile_y + py + r, gx = tile_x + tx + h * 16;
            bf16x8 pv;
            #pragma unroll
            for (int co = 0; co < 8; ++co)
                pv[co] = (short)f2bf(acc[r][h][co] + bias[cog * 8 + co]);
            *(bf16x8*)(out + (((((size_t)b << 14) + gy * 128 + gx)) << 7) + cog * 8) = pv;
        }
    }
}

// ---------------- main conv: implicit GEMM, bf16 MFMA -----------------------
// Block tile: 8 rows x 16 cols px; halo tile 10x18 px staged per 64-ch half
// (25.9 KB LDS). NSPLIT=1: wave = (wv>>1)*LM row-group x (wv&1)*NTW co-group.
// DOMEAN=1: accumulate post-relu output sums into meanb (SE fusion).
template <int LM, int NTW, int NSPLIT, int DOMEAN>
__global__ __launch_bounds__(256, 3) void conv_mfma(
    const unsigned short* __restrict__ in, const unsigned short* __restrict__ wT,
    size_t wstride, const float* __restrict__ bias, unsigned short* __restrict__ out,
    float* __restrict__ meanb, int Coutp, int Cout, int relu)
{
    __shared__ unsigned short lds[180 * 72];  // 10x18 px, 64 ch + 8 pad
    const int tid = threadIdx.x;
    const int b = blockIdx.y;
    const int row0 = (blockIdx.x >> 3) << 3;   // 16 row-tiles of 8
    const int col0 = (blockIdx.x & 7) << 4;    // 8 col-tiles of 16
    const int l = tid & 63, wv = tid >> 6;
    const int li = l & 15, lq = l >> 4;
    const int m_base = NSPLIT ? (wv >> 1) * LM : wv * LM;
    const int n_base = NSPLIT ? (wv & 1) * NTW : 0;
    const size_t inb = ((size_t)b) << 14;
    const unsigned short* wbase = wT + (size_t)b * wstride;

    f32x4 acc[LM][NTW];
    #pragma unroll
    for (int lm = 0; lm < LM; ++lm)
        #pragma unroll
        for (int nt = 0; nt < NTW; ++nt)
            acc[lm][nt] = (f32x4){0.f, 0.f, 0.f, 0.f};

    #pragma unroll 1
    for (int half = 0; half < 2; ++half) {
        __syncthreads();
        for (int u = tid; u < 1440; u += 256) {   // 180 px * 8 parts (64 ch)
            int px = u >> 3, part = u & 7;
            int hr = px / 18, hc = px - hr * 18;
            int gy = row0 - 1 + hr, gx = col0 - 1 + hc;
            bf16x8 v = {0, 0, 0, 0, 0, 0, 0, 0};
            if ((unsigned)gy < 128u && (unsigned)gx < 128u)
                v = *(const bf16x8*)(in + ((inb + (gy << 7) + gx) << 7) + half * 64 + part * 8);
            *(bf16x8*)(lds + px * 72 + part * 8) = v;
        }
        __syncthreads();

        auto loadB = [&](bf16x8 (&dst)[NTW], int s) {
            int tap = s >> 1, kcl = s & 1;
            const unsigned short* p = wbase +
                (size_t)(tap * 4 + half * 2 + kcl) * (Coutp * 32) +
                (n_base * 16 + li) * 32 + lq * 8;
            #pragma unroll
            for (int nt = 0; nt < NTW; ++nt)
                dst[nt] = *(const bf16x8*)(p + nt * 512);
        };
        auto compute = [&](bf16x8 (&bf)[NTW], int s) {
            int tap = s >> 1, kcl = s & 1;
            int ky = tap / 3, kx = tap - ky * 3;
            int coff = kcl * 32 + lq * 8;
            #pragma unroll
            for (int lm = 0; lm < LM; ++lm) {
                bf16x8 af = *(const bf16x8*)(
                    lds + ((m_base + lm + ky) * 18 + li + kx) * 72 + coff);
                #pragma unroll
                for (int nt = 0; nt < NTW; ++nt)
                    acc[lm][nt] = __builtin_amdgcn_mfma_f32_16x16x32_bf16(
                        af, bf[nt], acc[lm][nt], 0, 0, 0);
            }
        };

        bf16x8 bufA[NTW], bufB[NTW];
        loadB(bufA, 0);
        #pragma unroll 1
        for (int it = 0; it < 18; it += 2) {
            loadB(bufB, it + 1);
            compute(bufA, it);
            if (it + 2 < 18) loadB(bufA, it + 2);
            compute(bufB, it + 1);
        }
    }

    float bv[NTW], msum[NTW];
    #pragma unroll
    for (int nt = 0; nt < NTW; ++nt) {
        int co = (n_base + nt) * 16 + li;
        bv[nt] = (co < Cout) ? bias[co] : 0.f;
        msum[nt] = 0.f;
    }
    #pragma unroll
    for (int lm = 0; lm < LM; ++lm) {
        int row = row0 + m_base + lm;
        #pragma unroll
        for (int r = 0; r < 4; ++r) {
            int col = col0 + lq * 4 + r;
            size_t pbase = (inb + row * 128 + col) * (size_t)Coutp;
            #pragma unroll
            for (int nt = 0; nt < NTW; ++nt) {
                float v = acc[lm][nt][r] + bv[nt];
                if (relu) v = fmaxf(v, 0.f);
                if (DOMEAN) msum[nt] += v;
                out[pbase + (n_base + nt) * 16 + li] = f2bf(v);
            }
        }
    }
    if (DOMEAN) {
        #pragma unroll
        for (int nt = 0; nt < NTW; ++nt) {
            float t = msum[nt];
            t += __shfl_xor(t, 16, 64);
            t += __shfl_xor(t, 32, 64);
            if (lq == 0)
                atomicAdd(&meanb[b * 128 + (n_base + nt) * 16 + li], t);
        }
    }
}

// ---- weight transform: [Co][128][3][3] f32 -> [tap*4+kc][Coutp][32] bf16 ---
__global__ __launch_bounds__(256) void wtrans(
    const float* __restrict__ w, unsigned short* __restrict__ wT, int Co, int Coutp)
{
    int idx = blockIdx.x * 256 + threadIdx.x;
    if (idx >= 9 * 4 * Coutp * 32) return;
    int ch = idx & 31;
    int rest = idx >> 5;          // (tap*4+kc)*Coutp + co
    int co = rest % Coutp;
    int slice = rest / Coutp;
    int kc = slice & 3, tap = slice >> 2;
    float v = (co < Co) ? w[((size_t)(co * 128 + kc * 32 + ch)) * 9 + tap] : 0.f;
    wT[idx] = f2bf(v);
}

// ---- per-batch SE-scaled weight copies: out[b][...] = wT[...] * s[b][ci] ---
__global__ __launch_bounds__(256) void wscale8(
    const unsigned short* __restrict__ wT, const float* __restrict__ scale,
    unsigned short* __restrict__ out, int Coutp)
{
    int r = blockIdx.x * 256 + threadIdx.x;
    int b = blockIdx.y;
    int ch = r & 31;
    int slice = (r >> 5) / Coutp;
    int kc = slice & 3;
    float s = scale[b * 128 + kc * 32 + ch];
    out[(size_t)b * (9 * 4 * Coutp * 32) + r] = f2bf(bf2f(wT[r]) * s);
}

__global__ __launch_bounds__(128) void se_kernel(
    const float* __restrict__ meanb, const float* __restrict__ w1,
    const float* __restrict__ b1, const float* __restrict__ w2,
    const float* __restrict__ b2, float* __restrict__ scale)
{
    const int b = blockIdx.x, c = threadIdx.x;
    __shared__ float h1[8];
    if (c < 8) {
        float s = 0.f;
        for (int j = 0; j < 128; ++j) s += w1[c * 128 + j] * meanb[b * 128 + j];
        h1[c] = fmaxf(s * (1.f / 16384.f) + b1[c], 0.f);
    }
    __syncthreads();
    float s = b2[c];
    #pragma unroll
    for (int j = 0; j < 8; ++j) s += w2[c * 8 + j] * h1[j];
    scale[b * 128 + c] = 1.f / (1.f + expf(-s));
}

// ---------------- dynamic filter: wgt staged via LDS for coalescing ---------
__global__ __launch_bounds__(256) void dynfilter(
    const float* __restrict__ x, const unsigned short* __restrict__ wgt,
    const float* __restrict__ kern, float* __restrict__ out)
{
    __shared__ unsigned short wl[256 * 88];   // 256 px, 80 wgt + 8 pad (176 B/px)
    const int blk = blockIdx.x;               // 512 blocks
    const int b = blk >> 6;
    const int px0 = (blk & 63) << 8;

    const unsigned short* src = wgt + ((size_t)b * 16384 + px0) * 80;
    for (int u = threadIdx.x; u < 2560; u += 256) {   // coalesced 16B units
        int px = u / 10, k8 = u - px * 10;
        *(bf16x8*)(wl + px * 88 + k8 * 8) = *(const bf16x8*)(src + u * 8);
    }
    __syncthreads();

    const int pix = px0 + threadIdx.x;
    const int h = pix >> 7, w = pix & 127;
    const unsigned short* rowp = wl + threadIdx.x * 88;

    float e[25];
    #pragma unroll
    for (int i = 0; i < 25; ++i) e[i] = 0.f;
    #pragma unroll
    for (int u8 = 0; u8 < 9; ++u8) {          // 72 = 9*8 exactly
        bf16x8 wv8 = *(const bf16x8*)(rowp + u8 * 8);
        #pragma unroll
        for (int j = 0; j < 8; ++j) {
            float wk = bf2f((unsigned short)wv8[j]);
            const float* kp = kern + (u8 * 8 + j) * 25;   // lane-uniform -> s_load
            #pragma unroll
            for (int i = 0; i < 25; ++i) e[i] += wk * kp[i];
        }
    }

    int yy[5], xx[5];
    #pragma unroll
    for (int d = 0; d < 5; ++d) {
        int y = h - 2 + d;
        yy[d] = y < 0 ? -y : (y > 127 ? 254 - y : y);
        int xv = w - 2 + d;
        xx[d] = xv < 0 ? -xv : (xv > 127 ? 254 - xv : xv);
    }

    #pragma unroll
    for (int c = 0; c < 3; ++c) {
        const float* xc = x + ((size_t)(b * 3 + c) << 14);
        float s = 0.f;
        #pragma unroll
        for (int dy = 0; dy < 5; ++dy)
            #pragma unroll
            for (int dx = 0; dx < 5; ++dx)
                s += e[dy * 5 + dx] * xc[yy[dy] * 128 + xx[dx]];
        out[((size_t)(b * 3 + c) << 14) + pix] = s;
    }
}

// ---------------------------------------------------------------------------
extern "C" void kernel_launch(void* const* d_in, const int* in_sizes, int n_in,
                              void* d_out, int out_size, void* d_ws, size_t ws_size,
                              hipStream_t stream)
{
    const float* x      = (const float*)d_in[0];
    const float* w_head = (const float*)d_in[1];
    const float* b_head = (const float*)d_in[2];
    const float* w_h1a  = (const float*)d_in[3];
    const float* b_h1a  = (const float*)d_in[4];
    const float* w_h1b  = (const float*)d_in[5];
    const float* b_h1b  = (const float*)d_in[6];
    const float* du1_w1 = (const float*)d_in[7];
    const float* du1_b1 = (const float*)d_in[8];
    const float* du1_w2 = (const float*)d_in[9];
    const float* du1_b2 = (const float*)d_in[10];
    const float* w_h2a  = (const float*)d_in[11];
    const float* b_h2a  = (const float*)d_in[12];
    const float* w_h2b  = (const float*)d_in[13];
    const float* b_h2b  = (const float*)d_in[14];
    const float* du2_w1 = (const float*)d_in[15];
    const float* du2_b1 = (const float*)d_in[16];
    const float* du2_w2 = (const float*)d_in[17];
    const float* du2_b2 = (const float*)d_in[18];
    const float* w_tail = (const float*)d_in[19];
    const float* b_tail = (const float*)d_in[20];
    const float* kern   = (const float*)d_in[21];
    float* out = (float*)d_out;

    unsigned short* fb0  = (unsigned short*)d_ws;        // 16,777,216 elems
    unsigned short* fb1  = fb0 + 16777216;
    unsigned short* wgtb = fb1 + 16777216;               // 8*16384*80
    unsigned short* wt1  = wgtb + 10485760;              // 9*4*128*32 = 147456 each
    unsigned short* wt2  = wt1 + 147456;
    unsigned short* wt3  = wt2 + 147456;
    unsigned short* wt4  = wt3 + 147456;
    unsigned short* wtt  = wt4 + 147456;                 // 9*4*80*32 = 92160
    unsigned short* wsa  = wtt + 92160;                  // 8x scaled h2a weights
    unsigned short* wst  = wsa + 8 * 147456;             // 8x scaled tail weights
    float* mean1  = (float*)(wst + 8 * 92160);           // 1024
    float* mean2  = mean1 + 1024;
    float* scaleb = mean2 + 1024;

    dim3 blk(256);
    hipMemsetAsync(mean1, 0, 8192, stream);              // zero mean1+mean2

    wtrans<<<576, blk, 0, stream>>>(w_h1a, wt1, 128, 128);
    wtrans<<<576, blk, 0, stream>>>(w_h1b, wt2, 128, 128);
    wtrans<<<576, blk, 0, stream>>>(w_h2a, wt3, 128, 128);
    wtrans<<<576, blk, 0, stream>>>(w_h2b, wt4, 128, 128);
    wtrans<<<360, blk, 0, stream>>>(w_tail, wtt, 72, 80);

    head_conv<<<dim3(16, 16, 8), blk, 0, stream>>>(x, w_head, b_head, fb0);

    dim3 cgrid(128, 8);
    conv_mfma<4, 4, 1, 0><<<cgrid, blk, 0, stream>>>(fb0, wt1, 0, b_h1a, fb1, nullptr, 128, 128, 1);
    conv_mfma<4, 4, 1, 1><<<cgrid, blk, 0, stream>>>(fb1, wt2, 0, b_h1b, fb0, mean1, 128, 128, 1);

    se_kernel<<<8, 128, 0, stream>>>(mean1, du1_w1, du1_b1, du1_w2, du1_b2, scaleb);
    wscale8<<<dim3(576, 8), blk, 0, stream>>>(wt3, scaleb, wsa, 128);

    conv_mfma<4, 4, 1, 0><<<cgrid, blk, 0, stream>>>(fb0, wsa, 147456, b_h2a, fb1, nullptr, 128, 128, 1);
    conv_mfma<4, 4, 1, 1><<<cgrid, blk, 0, stream>>>(fb1, wt4, 0, b_h2b, fb0, mean2, 128, 128, 1);

    se_kernel<<<8, 128, 0, stream>>>(mean2, du2_w1, du2_b1, du2_w2, du2_b2, scaleb);
    wscale8<<<dim3(360, 8), blk, 0, stream>>>(wtt, scaleb, wst, 80);

    conv_mfma<2, 5, 0, 0><<<cgrid, blk, 0, stream>>>(fb0, wst, 92160, b_tail, wgtb, nullptr, 80, 72, 0);

    dynfilter<<<512, blk, 0, stream>>>(x, wgtb, kern, out);
}

// Round 8
// 431.740 us; speedup vs baseline: 1.1074x; 1.1074x over previous
//
#include <hip/hip_runtime.h>
#include <math.h>

// ---------------------------------------------------------------------------
// R8: R6 conv shape (16x16 px, LM=8) + N-split across blocks (1024 blocks,
// 64 co each, NTW=2/wave): same B:MFMA intensity, 2x blocks/CU for latency
// hiding. DOMEAN epilogue fusion kept from R7. Tail conv padded to 96 co.
// wtrans x4 merged into one launch.
// ---------------------------------------------------------------------------

typedef __attribute__((ext_vector_type(8))) short bf16x8;
typedef __attribute__((ext_vector_type(4))) float f32x4;

__device__ inline float bf2f(unsigned short u) {
    unsigned v = ((unsigned)u) << 16;
    return __builtin_bit_cast(float, v);
}
__device__ inline unsigned short f2bf(float f) {
    unsigned u = __builtin_bit_cast(unsigned, f);
    u += 0x7FFF + ((u >> 16) & 1);   // RNE
    return (unsigned short)(u >> 16);
}

// ---------------- head conv: fp32 NCHW (Cin=3) -> NHWC bf16 (C=128) ---------
__global__ __launch_bounds__(256) void head_conv(
    const float* __restrict__ x, const float* __restrict__ w,
    const float* __restrict__ bias, unsigned short* __restrict__ out)
{
    __shared__ float wlds[216];          // [ci][tap][co8]
    __shared__ float tile[3][34 * 34];
    const int tid = threadIdx.x, cog = blockIdx.y, b = blockIdx.z;
    const int tile_y = (blockIdx.x >> 2) * 32, tile_x = (blockIdx.x & 3) * 32;

    if (tid < 216) {
        int co = tid & 7, rest = tid >> 3, tap = rest % 9, ci = rest / 9;
        wlds[tid] = w[((cog * 8 + co) * 3 + ci) * 9 + tap];
    }
    for (int idx = tid; idx < 3 * 34 * 34; idx += 256) {
        int ci = idx / 1156, rem = idx - ci * 1156;
        int r = rem / 34, c = rem - r * 34;
        int gy = tile_y - 1 + r, gx = tile_x - 1 + c;
        float v = 0.f;
        if ((unsigned)gy < 128u && (unsigned)gx < 128u)
            v = x[(((size_t)(b * 3 + ci)) << 14) + (gy << 7) + gx];
        tile[ci][rem] = v;
    }
    __syncthreads();

    const int ty = tid >> 4, tx = tid & 15, py = ty * 2;
    float acc[2][2][8];
    #pragma unroll
    for (int r = 0; r < 2; ++r)
        #pragma unroll
        for (int h = 0; h < 2; ++h)
            #pragma unroll
            for (int co = 0; co < 8; ++co) acc[r][h][co] = 0.f;

    #pragma unroll
    for (int ci = 0; ci < 3; ++ci) {
        #pragma unroll
        for (int ky = 0; ky < 3; ++ky) {
            #pragma unroll
            for (int kx = 0; kx < 3; ++kx) {
                const float* wp = wlds + (ci * 9 + ky * 3 + kx) * 8;
                float i00 = tile[ci][(py + ky) * 34 + tx + kx];
                float i01 = tile[ci][(py + ky) * 34 + tx + 16 + kx];
                float i10 = tile[ci][(py + 1 + ky) * 34 + tx + kx];
                float i11 = tile[ci][(py + 1 + ky) * 34 + tx + 16 + kx];
                #pragma unroll
                for (int co = 0; co < 8; ++co) {
                    float wv = wp[co];
                    acc[0][0][co] += i00 * wv;
                    acc[0][1][co] += i01 * wv;
                    acc[1][0][co] += i10 * wv;
                    acc[1][1][co] += i11 * wv;
                }
            }
        }
    }

    #pragma unroll
    for (int r = 0; r < 2; ++r) {
        #pragma unroll
        for (int h = 0; h < 2; ++h) {
            int gy = tile_y + py + r, gx = tile_x + tx + h * 16;
            bf16x8 pv;
            #pragma unroll
            for (int co = 0; co < 8; ++co)
                pv[co] = (short)f2bf(acc[r][h][co] + bias[cog * 8 + co]);
            *(bf16x8*)(out + (((((size_t)b << 14) + gy * 128 + gx)) << 7) + cog * 8) = pv;
        }
    }
}

// ---------------- main conv: implicit GEMM, bf16 MFMA -----------------------
// Block: 16x16 px tile, A staged in two 64-ch halves (46.6 KB LDS).
// N split across blockIdx.y (each block NTW*(WNSPLIT+1) n-tiles of 16 co).
// WNSPLIT=1: waves tile 2 m-groups x 2 n-groups. DOMEAN: fused SE mean.
template <int LM, int NTW, int WNSPLIT, int DOMEAN>
__global__ __launch_bounds__(256, 3) void conv_mfma(
    const unsigned short* __restrict__ in, const unsigned short* __restrict__ wT,
    size_t wstride, const float* __restrict__ bias, unsigned short* __restrict__ out,
    float* __restrict__ meanb, int Coutp, int Cout, int relu)
{
    __shared__ unsigned short lds[324 * 72];  // 18x18 px, 64 ch + 8 pad
    const int tid = threadIdx.x;
    const int b = blockIdx.z;
    const int row0 = (blockIdx.x >> 3) << 4;
    const int col0 = (blockIdx.x & 7) << 4;
    const int l = tid & 63, wv = tid >> 6;
    const int li = l & 15, lq = l >> 4;
    const int m_base = WNSPLIT ? (wv >> 1) * LM : wv * LM;
    const int n_base = blockIdx.y * (NTW * (WNSPLIT + 1)) +
                       (WNSPLIT ? (wv & 1) * NTW : 0);
    const size_t inb = ((size_t)b) << 14;
    const unsigned short* wbase = wT + (size_t)b * wstride;

    f32x4 acc[LM][NTW];
    #pragma unroll
    for (int lm = 0; lm < LM; ++lm)
        #pragma unroll
        for (int nt = 0; nt < NTW; ++nt)
            acc[lm][nt] = (f32x4){0.f, 0.f, 0.f, 0.f};

    #pragma unroll 1
    for (int half = 0; half < 2; ++half) {
        __syncthreads();
        for (int u = tid; u < 2592; u += 256) {   // 324 px * 8 parts (64 ch)
            int px = u >> 3, part = u & 7;
            int hr = px / 18, hc = px - hr * 18;
            int gy = row0 - 1 + hr, gx = col0 - 1 + hc;
            bf16x8 v = {0, 0, 0, 0, 0, 0, 0, 0};
            if ((unsigned)gy < 128u && (unsigned)gx < 128u)
                v = *(const bf16x8*)(in + ((inb + (gy << 7) + gx) << 7) + half * 64 + part * 8);
            *(bf16x8*)(lds + px * 72 + part * 8) = v;
        }
        __syncthreads();

        auto loadB = [&](bf16x8 (&dst)[NTW], int s) {
            int tap = s >> 1, kcl = s & 1;
            const unsigned short* p = wbase +
                (size_t)(tap * 4 + half * 2 + kcl) * (Coutp * 32) +
                (n_base * 16 + li) * 32 + lq * 8;
            #pragma unroll
            for (int nt = 0; nt < NTW; ++nt)
                dst[nt] = *(const bf16x8*)(p + nt * 512);
        };
        auto compute = [&](bf16x8 (&bf)[NTW], int s) {
            int tap = s >> 1, kcl = s & 1;
            int ky = tap / 3, kx = tap - ky * 3;
            int coff = kcl * 32 + lq * 8;
            #pragma unroll
            for (int lm = 0; lm < LM; ++lm) {
                bf16x8 af = *(const bf16x8*)(
                    lds + ((m_base + lm + ky) * 18 + li + kx) * 72 + coff);
                #pragma unroll
                for (int nt = 0; nt < NTW; ++nt)
                    acc[lm][nt] = __builtin_amdgcn_mfma_f32_16x16x32_bf16(
                        af, bf[nt], acc[lm][nt], 0, 0, 0);
            }
        };

        bf16x8 bufA[NTW], bufB[NTW];
        loadB(bufA, 0);
        #pragma unroll 1
        for (int it = 0; it < 18; it += 2) {
            loadB(bufB, it + 1);
            compute(bufA, it);
            if (it + 2 < 18) loadB(bufA, it + 2);
            compute(bufB, it + 1);
        }
    }

    float bv[NTW], msum[NTW];
    #pragma unroll
    for (int nt = 0; nt < NTW; ++nt) {
        int co = (n_base + nt) * 16 + li;
        bv[nt] = (co < Cout) ? bias[co] : 0.f;
        msum[nt] = 0.f;
    }
    #pragma unroll
    for (int lm = 0; lm < LM; ++lm) {
        int row = row0 + m_base + lm;
        #pragma unroll
        for (int r = 0; r < 4; ++r) {
            int col = col0 + lq * 4 + r;
            size_t pbase = (inb + row * 128 + col) * (size_t)Coutp;
            #pragma unroll
            for (int nt = 0; nt < NTW; ++nt) {
                float v = acc[lm][nt][r] + bv[nt];
                if (relu) v = fmaxf(v, 0.f);
                if (DOMEAN) msum[nt] += v;
                out[pbase + (n_base + nt) * 16 + li] = f2bf(v);
            }
        }
    }
    if (DOMEAN) {
        #pragma unroll
        for (int nt = 0; nt < NTW; ++nt) {
            float t = msum[nt];
            t += __shfl_xor(t, 16, 64);
            t += __shfl_xor(t, 32, 64);
            if (lq == 0)
                atomicAdd(&meanb[b * 128 + (n_base + nt) * 16 + li], t);
        }
    }
}

// ---- weight transform: [Co][128][3][3] f32 -> [tap*4+kc][Coutp][32] bf16 ---
__device__ inline void wtrans_one(const float* w, unsigned short* wT,
                                  int Co, int Coutp, int idx)
{
    int ch = idx & 31;
    int rest = idx >> 5;
    int co = rest % Coutp;
    int slice = rest / Coutp;
    int kc = slice & 3, tap = slice >> 2;
    float v = (co < Co) ? w[((size_t)(co * 128 + kc * 32 + ch)) * 9 + tap] : 0.f;
    wT[idx] = f2bf(v);
}

__global__ __launch_bounds__(256) void wtrans4(
    const float* __restrict__ w0, const float* __restrict__ w1,
    const float* __restrict__ w2, const float* __restrict__ w3,
    unsigned short* __restrict__ t0, unsigned short* __restrict__ t1,
    unsigned short* __restrict__ t2, unsigned short* __restrict__ t3)
{
    int idx = blockIdx.x * 256 + threadIdx.x;   // 147456 each
    const float* w = blockIdx.y == 0 ? w0 : blockIdx.y == 1 ? w1 : blockIdx.y == 2 ? w2 : w3;
    unsigned short* t = blockIdx.y == 0 ? t0 : blockIdx.y == 1 ? t1 : blockIdx.y == 2 ? t2 : t3;
    wtrans_one(w, t, 128, 128, idx);
}

__global__ __launch_bounds__(256) void wtrans(
    const float* __restrict__ w, unsigned short* __restrict__ wT, int Co, int Coutp)
{
    int idx = blockIdx.x * 256 + threadIdx.x;
    if (idx >= 9 * 4 * Coutp * 32) return;
    wtrans_one(w, wT, Co, Coutp, idx);
}

// ---- per-batch SE-scaled weight copies: out[b][...] = wT[...] * s[b][ci] ---
__global__ __launch_bounds__(256) void wscale8(
    const unsigned short* __restrict__ wT, const float* __restrict__ scale,
    unsigned short* __restrict__ out, int Coutp)
{
    int r = blockIdx.x * 256 + threadIdx.x;
    int b = blockIdx.y;
    int ch = r & 31;
    int slice = (r >> 5) / Coutp;
    int kc = slice & 3;
    float s = scale[b * 128 + kc * 32 + ch];
    out[(size_t)b * (9 * 4 * Coutp * 32) + r] = f2bf(bf2f(wT[r]) * s);
}

__global__ __launch_bounds__(128) void se_kernel(
    const float* __restrict__ meanb, const float* __restrict__ w1,
    const float* __restrict__ b1, const float* __restrict__ w2,
    const float* __restrict__ b2, float* __restrict__ scale)
{
    const int b = blockIdx.x, c = threadIdx.x;
    __shared__ float h1[8];
    if (c < 8) {
        float s = 0.f;
        for (int j = 0; j < 128; ++j) s += w1[c * 128 + j] * meanb[b * 128 + j];
        h1[c] = fmaxf(s * (1.f / 16384.f) + b1[c], 0.f);
    }
    __syncthreads();
    float s = b2[c];
    #pragma unroll
    for (int j = 0; j < 8; ++j) s += w2[c * 8 + j] * h1[j];
    scale[b * 128 + c] = 1.f / (1.f + expf(-s));
}

// ---------------- dynamic filter: wgt (stride 96) staged via LDS -----------
__global__ __launch_bounds__(256) void dynfilter(
    const float* __restrict__ x, const unsigned short* __restrict__ wgt,
    const float* __restrict__ kern, float* __restrict__ out)
{
    __shared__ unsigned short wl[256 * 104];  // 256 px, 96 wgt + 8 pad
    const int blk = blockIdx.x;               // 512 blocks
    const int b = blk >> 6;
    const int px0 = (blk & 63) << 8;

    const unsigned short* src = wgt + ((size_t)b * 16384 + px0) * 96;
    for (int u = threadIdx.x; u < 3072; u += 256) {   // coalesced 16B units
        int px = u / 12, k8 = u - px * 12;
        *(bf16x8*)(wl + px * 104 + k8 * 8) = *(const bf16x8*)(src + u * 8);
    }
    __syncthreads();

    const int pix = px0 + threadIdx.x;
    const int h = pix >> 7, w = pix & 127;
    const unsigned short* rowp = wl + threadIdx.x * 104;

    float e[25];
    #pragma unroll
    for (int i = 0; i < 25; ++i) e[i] = 0.f;
    #pragma unroll
    for (int u8 = 0; u8 < 9; ++u8) {          // 72 = 9*8 exactly
        bf16x8 wv8 = *(const bf16x8*)(rowp + u8 * 8);
        #pragma unroll
        for (int j = 0; j < 8; ++j) {
            float wk = bf2f((unsigned short)wv8[j]);
            const float* kp = kern + (u8 * 8 + j) * 25;   // lane-uniform -> s_load
            #pragma unroll
            for (int i = 0; i < 25; ++i) e[i] += wk * kp[i];
        }
    }

    int yy[5], xx[5];
    #pragma unroll
    for (int d = 0; d < 5; ++d) {
        int y = h - 2 + d;
        yy[d] = y < 0 ? -y : (y > 127 ? 254 - y : y);
        int xv = w - 2 + d;
        xx[d] = xv < 0 ? -xv : (xv > 127 ? 254 - xv : xv);
    }

    #pragma unroll
    for (int c = 0; c < 3; ++c) {
        const float* xc = x + ((size_t)(b * 3 + c) << 14);
        float s = 0.f;
        #pragma unroll
        for (int dy = 0; dy < 5; ++dy)
            #pragma unroll
            for (int dx = 0; dx < 5; ++dx)
                s += e[dy * 5 + dx] * xc[yy[dy] * 128 + xx[dx]];
        out[((size_t)(b * 3 + c) << 14) + pix] = s;
    }
}

// ---------------------------------------------------------------------------
extern "C" void kernel_launch(void* const* d_in, const int* in_sizes, int n_in,
                              void* d_out, int out_size, void* d_ws, size_t ws_size,
                              hipStream_t stream)
{
    const float* x      = (const float*)d_in[0];
    const float* w_head = (const float*)d_in[1];
    const float* b_head = (const float*)d_in[2];
    const float* w_h1a  = (const float*)d_in[3];
    const float* b_h1a  = (const float*)d_in[4];
    const float* w_h1b  = (const float*)d_in[5];
    const float* b_h1b  = (const float*)d_in[6];
    const float* du1_w1 = (const float*)d_in[7];
    const float* du1_b1 = (const float*)d_in[8];
    const float* du1_w2 = (const float*)d_in[9];
    const float* du1_b2 = (const float*)d_in[10];
    const float* w_h2a  = (const float*)d_in[11];
    const float* b_h2a  = (const float*)d_in[12];
    const float* w_h2b  = (const float*)d_in[13];
    const float* b_h2b  = (const float*)d_in[14];
    const float* du2_w1 = (const float*)d_in[15];
    const float* du2_b1 = (const float*)d_in[16];
    const float* du2_w2 = (const float*)d_in[17];
    const float* du2_b2 = (const float*)d_in[18];
    const float* w_tail = (const float*)d_in[19];
    const float* b_tail = (const float*)d_in[20];
    const float* kern   = (const float*)d_in[21];
    float* out = (float*)d_out;

    unsigned short* fb0  = (unsigned short*)d_ws;        // 16,777,216 elems
    unsigned short* fb1  = fb0 + 16777216;
    unsigned short* wgtb = fb1 + 16777216;               // 8*16384*96
    unsigned short* wt1  = wgtb + 12582912;              // 9*4*128*32 = 147456 each
    unsigned short* wt2  = wt1 + 147456;
    unsigned short* wt3  = wt2 + 147456;
    unsigned short* wt4  = wt3 + 147456;
    unsigned short* wtt  = wt4 + 147456;                 // 9*4*96*32 = 110592
    unsigned short* wsa  = wtt + 110592;                 // 8x scaled h2a weights
    unsigned short* wst  = wsa + 8 * 147456;             // 8x scaled tail weights
    float* mean1  = (float*)(wst + 8 * 110592);          // 1024
    float* mean2  = mean1 + 1024;
    float* scaleb = mean2 + 1024;

    dim3 blk(256);
    hipMemsetAsync(mean1, 0, 8192, stream);              // zero mean1+mean2

    wtrans4<<<dim3(576, 4), blk, 0, stream>>>(w_h1a, w_h1b, w_h2a, w_h2b,
                                              wt1, wt2, wt3, wt4);
    wtrans<<<432, blk, 0, stream>>>(w_tail, wtt, 72, 96);

    head_conv<<<dim3(16, 16, 8), blk, 0, stream>>>(x, w_head, b_head, fb0);

    dim3 cgrid(64, 2, 8);   // 1024 blocks, 64 couts each
    conv_mfma<8, 2, 1, 0><<<cgrid, blk, 0, stream>>>(fb0, wt1, 0, b_h1a, fb1, nullptr, 128, 128, 1);
    conv_mfma<8, 2, 1, 1><<<cgrid, blk, 0, stream>>>(fb1, wt2, 0, b_h1b, fb0, mean1, 128, 128, 1);

    se_kernel<<<8, 128, 0, stream>>>(mean1, du1_w1, du1_b1, du1_w2, du1_b2, scaleb);
    wscale8<<<dim3(576, 8), blk, 0, stream>>>(wt3, scaleb, wsa, 128);

    conv_mfma<8, 2, 1, 0><<<cgrid, blk, 0, stream>>>(fb0, wsa, 147456, b_h2a, fb1, nullptr, 128, 128, 1);
    conv_mfma<8, 2, 1, 1><<<cgrid, blk, 0, stream>>>(fb1, wt4, 0, b_h2b, fb0, mean2, 128, 128, 1);

    se_kernel<<<8, 128, 0, stream>>>(mean2, du2_w1, du2_b1, du2_w2, du2_b2, scaleb);
    wscale8<<<dim3(432, 8), blk, 0, stream>>>(wtt, scaleb, wst, 96);

    conv_mfma<4, 3, 0, 0><<<cgrid, blk, 0, stream>>>(fb0, wst, 110592, b_tail, wgtb, nullptr, 96, 72, 0);

    dynfilter<<<512, blk, 0, stream>>>(x, wgtb, kern, out);
}

// Round 9
// 359.347 us; speedup vs baseline: 1.3305x; 1.2015x over previous
//
#include <hip/hip_runtime.h>
#include <math.h>

// ---------------------------------------------------------------------------
// R9: R6 conv shape (16x16 px, LM=8 NTW=4 wave-split, grid 512) restored.
// + XOR-swizzled unpadded LDS (conflict-free af reads), + DOMEAN SE-mean
// fusion, + dynfilter fused into tail conv epilogue (wgtb round-trip gone),
// + SE FC fused into wscale8. 10 launches (was 14).
// ---------------------------------------------------------------------------

typedef __attribute__((ext_vector_type(8))) short bf16x8;
typedef __attribute__((ext_vector_type(4))) float f32x4;

__device__ inline float bf2f(unsigned short u) {
    unsigned v = ((unsigned)u) << 16;
    return __builtin_bit_cast(float, v);
}
__device__ inline unsigned short f2bf(float f) {
    unsigned u = __builtin_bit_cast(unsigned, f);
    u += 0x7FFF + ((u >> 16) & 1);   // RNE
    return (unsigned short)(u >> 16);
}

// ---------------- head conv: fp32 NCHW (Cin=3) -> NHWC bf16 (C=128) ---------
__global__ __launch_bounds__(256) void head_conv(
    const float* __restrict__ x, const float* __restrict__ w,
    const float* __restrict__ bias, unsigned short* __restrict__ out)
{
    __shared__ float wlds[216];          // [ci][tap][co8]
    __shared__ float tile[3][34 * 34];
    const int tid = threadIdx.x, cog = blockIdx.y, b = blockIdx.z;
    const int tile_y = (blockIdx.x >> 2) * 32, tile_x = (blockIdx.x & 3) * 32;

    if (tid < 216) {
        int co = tid & 7, rest = tid >> 3, tap = rest % 9, ci = rest / 9;
        wlds[tid] = w[((cog * 8 + co) * 3 + ci) * 9 + tap];
    }
    for (int idx = tid; idx < 3 * 34 * 34; idx += 256) {
        int ci = idx / 1156, rem = idx - ci * 1156;
        int r = rem / 34, c = rem - r * 34;
        int gy = tile_y - 1 + r, gx = tile_x - 1 + c;
        float v = 0.f;
        if ((unsigned)gy < 128u && (unsigned)gx < 128u)
            v = x[(((size_t)(b * 3 + ci)) << 14) + (gy << 7) + gx];
        tile[ci][rem] = v;
    }
    __syncthreads();

    const int ty = tid >> 4, tx = tid & 15, py = ty * 2;
    float acc[2][2][8];
    #pragma unroll
    for (int r = 0; r < 2; ++r)
        #pragma unroll
        for (int h = 0; h < 2; ++h)
            #pragma unroll
            for (int co = 0; co < 8; ++co) acc[r][h][co] = 0.f;

    #pragma unroll
    for (int ci = 0; ci < 3; ++ci) {
        #pragma unroll
        for (int ky = 0; ky < 3; ++ky) {
            #pragma unroll
            for (int kx = 0; kx < 3; ++kx) {
                const float* wp = wlds + (ci * 9 + ky * 3 + kx) * 8;
                float i00 = tile[ci][(py + ky) * 34 + tx + kx];
                float i01 = tile[ci][(py + ky) * 34 + tx + 16 + kx];
                float i10 = tile[ci][(py + 1 + ky) * 34 + tx + kx];
                float i11 = tile[ci][(py + 1 + ky) * 34 + tx + 16 + kx];
                #pragma unroll
                for (int co = 0; co < 8; ++co) {
                    float wv = wp[co];
                    acc[0][0][co] += i00 * wv;
                    acc[0][1][co] += i01 * wv;
                    acc[1][0][co] += i10 * wv;
                    acc[1][1][co] += i11 * wv;
                }
            }
        }
    }

    #pragma unroll
    for (int r = 0; r < 2; ++r) {
        #pragma unroll
        for (int h = 0; h < 2; ++h) {
            int gy = tile_y + py + r, gx = tile_x + tx + h * 16;
            bf16x8 pv;
            #pragma unroll
            for (int co = 0; co < 8; ++co)
                pv[co] = (short)f2bf(acc[r][h][co] + bias[cog * 8 + co]);
            *(bf16x8*)(out + (((((size_t)b << 14) + gy * 128 + gx)) << 7) + cog * 8) = pv;
        }
    }
}

// ---------------- main conv: implicit GEMM, bf16 MFMA -----------------------
// Block: 16x16 px tile; A staged in two 64-ch halves, UNPADDED stride 64 ush
// with XOR swizzle (channel-group p = g ^ (px&7)) -> conflict-free b128 reads.
// WNSPLIT=1: 4 waves tile 2 m-groups x 2 n-groups (LM=8, NTW=4 for 128 co).
// DOMEAN: fused SE pooled-sum. TAILFUSE: dynfilter fused into epilogue.
template <int LM, int NTW, int WNSPLIT, int DOMEAN, int TAILFUSE>
__global__ __launch_bounds__(256, 2) void conv_mfma(
    const unsigned short* __restrict__ in, const unsigned short* __restrict__ wT,
    size_t wstride, const float* __restrict__ bias, unsigned short* __restrict__ out,
    float* __restrict__ meanb, const float* __restrict__ x,
    const float* __restrict__ kern, float* __restrict__ outf,
    int Coutp, int Cout, int relu)
{
    __shared__ unsigned short lds[TAILFUSE ? 256 * 88 : 324 * 64];
    const int tid = threadIdx.x;
    const int b = blockIdx.y;
    const int row0 = (blockIdx.x >> 3) << 4;
    const int col0 = (blockIdx.x & 7) << 4;
    const int l = tid & 63, wv = tid >> 6;
    const int li = l & 15, lq = l >> 4;
    const int m_base = WNSPLIT ? (wv >> 1) * LM : wv * LM;
    const int n_base = WNSPLIT ? (wv & 1) * NTW : 0;
    const size_t inb = ((size_t)b) << 14;
    const unsigned short* wbase = wT + (size_t)b * wstride;

    f32x4 acc[LM][NTW];
    #pragma unroll
    for (int lm = 0; lm < LM; ++lm)
        #pragma unroll
        for (int nt = 0; nt < NTW; ++nt)
            acc[lm][nt] = (f32x4){0.f, 0.f, 0.f, 0.f};

    #pragma unroll 1
    for (int half = 0; half < 2; ++half) {
        __syncthreads();
        for (int u = tid; u < 2592; u += 256) {   // 324 px * 8 ch-groups
            int px = u >> 3, g = u & 7;
            int hr = px / 18, hc = px - hr * 18;
            int gy = row0 - 1 + hr, gx = col0 - 1 + hc;
            bf16x8 v = {0, 0, 0, 0, 0, 0, 0, 0};
            if ((unsigned)gy < 128u && (unsigned)gx < 128u)
                v = *(const bf16x8*)(in + ((inb + (gy << 7) + gx) << 7) + half * 64 + g * 8);
            int p = g ^ (px & 7);                 // XOR swizzle
            *(bf16x8*)(lds + px * 64 + p * 8) = v;
        }
        __syncthreads();

        auto loadB = [&](bf16x8 (&dst)[NTW], int s) {
            int tap = s >> 1, kcl = s & 1;
            const unsigned short* p = wbase +
                (size_t)(tap * 4 + half * 2 + kcl) * (Coutp * 32) +
                (n_base * 16 + li) * 32 + lq * 8;
            #pragma unroll
            for (int nt = 0; nt < NTW; ++nt)
                dst[nt] = *(const bf16x8*)(p + nt * 512);
        };
        auto compute = [&](bf16x8 (&bf)[NTW], int s) {
            int tap = s >> 1, kcl = s & 1;
            int ky = tap / 3, kx = tap - ky * 3;
            int g = kcl * 4 + lq;
            #pragma unroll
            for (int lm = 0; lm < LM; ++lm) {
                int px = (m_base + lm + ky) * 18 + li + kx;
                bf16x8 af = *(const bf16x8*)(lds + px * 64 + ((g ^ (px & 7)) * 8));
                #pragma unroll
                for (int nt = 0; nt < NTW; ++nt)
                    acc[lm][nt] = __builtin_amdgcn_mfma_f32_16x16x32_bf16(
                        af, bf[nt], acc[lm][nt], 0, 0, 0);
            }
        };

        bf16x8 bufA[NTW], bufB[NTW];
        loadB(bufA, 0);
        #pragma unroll 1
        for (int it = 0; it < 18; it += 2) {
            loadB(bufB, it + 1);
            compute(bufA, it);
            if (it + 2 < 18) loadB(bufA, it + 2);
            compute(bufB, it + 1);
        }
    }

    float bv[NTW], msum[NTW];
    #pragma unroll
    for (int nt = 0; nt < NTW; ++nt) {
        int co = (n_base + nt) * 16 + li;
        bv[nt] = (co < Cout) ? bias[co] : 0.f;
        msum[nt] = 0.f;
    }

    if (TAILFUSE) {
        __syncthreads();   // done with af region; reuse LDS for wgt staging
        #pragma unroll
        for (int lm = 0; lm < LM; ++lm) {
            int rowl = m_base + lm;
            #pragma unroll
            for (int r = 0; r < 4; ++r) {
                int coll = lq * 4 + r;
                #pragma unroll
                for (int nt = 0; nt < NTW; ++nt) {
                    int co = nt * 16 + li;
                    if (co < 72)
                        lds[(rowl * 16 + coll) * 88 + co] = f2bf(acc[lm][nt][r] + bv[nt]);
                }
            }
        }
        __syncthreads();

        const int h = row0 + (tid >> 4), w = col0 + (tid & 15);
        const int pix = h * 128 + w;
        const unsigned short* rowp = lds + tid * 88;

        float e[25];
        #pragma unroll
        for (int i = 0; i < 25; ++i) e[i] = 0.f;
        #pragma unroll
        for (int u8 = 0; u8 < 9; ++u8) {
            bf16x8 wv8 = *(const bf16x8*)(rowp + u8 * 8);
            #pragma unroll
            for (int j = 0; j < 8; ++j) {
                float wk = bf2f((unsigned short)wv8[j]);
                const float* kp = kern + (u8 * 8 + j) * 25;   // lane-uniform
                #pragma unroll
                for (int i = 0; i < 25; ++i) e[i] += wk * kp[i];
            }
        }

        int yy[5], xx[5];
        #pragma unroll
        for (int d = 0; d < 5; ++d) {
            int y = h - 2 + d;
            yy[d] = y < 0 ? -y : (y > 127 ? 254 - y : y);
            int xv = w - 2 + d;
            xx[d] = xv < 0 ? -xv : (xv > 127 ? 254 - xv : xv);
        }
        #pragma unroll
        for (int c = 0; c < 3; ++c) {
            const float* xc = x + ((size_t)(b * 3 + c) << 14);
            float s = 0.f;
            #pragma unroll
            for (int dy = 0; dy < 5; ++dy)
                #pragma unroll
                for (int dx = 0; dx < 5; ++dx)
                    s += e[dy * 5 + dx] * xc[yy[dy] * 128 + xx[dx]];
            outf[((size_t)(b * 3 + c) << 14) + pix] = s;
        }
        return;
    }

    #pragma unroll
    for (int lm = 0; lm < LM; ++lm) {
        int row = row0 + m_base + lm;
        #pragma unroll
        for (int r = 0; r < 4; ++r) {
            int col = col0 + lq * 4 + r;
            size_t pbase = (inb + row * 128 + col) * (size_t)Coutp;
            #pragma unroll
            for (int nt = 0; nt < NTW; ++nt) {
                float v = acc[lm][nt][r] + bv[nt];
                if (relu) v = fmaxf(v, 0.f);
                if (DOMEAN) msum[nt] += v;
                out[pbase + (n_base + nt) * 16 + li] = f2bf(v);
            }
        }
    }
    if (DOMEAN) {
        #pragma unroll
        for (int nt = 0; nt < NTW; ++nt) {
            float t = msum[nt];
            t += __shfl_xor(t, 16, 64);
            t += __shfl_xor(t, 32, 64);
            if (lq == 0)
                atomicAdd(&meanb[b * 128 + (n_base + nt) * 16 + li], t);
        }
    }
}

// ---- weight transform: [Co][128][3][3] f32 -> [tap*4+kc][Coutp][32] bf16 ---
__device__ inline void wtrans_one(const float* w, unsigned short* wT,
                                  int Co, int Coutp, int idx)
{
    int ch = idx & 31;
    int rest = idx >> 5;
    int co = rest % Coutp;
    int slice = rest / Coutp;
    int kc = slice & 3, tap = slice >> 2;
    float v = (co < Co) ? w[((size_t)(co * 128 + kc * 32 + ch)) * 9 + tap] : 0.f;
    wT[idx] = f2bf(v);
}

__global__ __launch_bounds__(256) void wtrans5(
    const float* __restrict__ w0, const float* __restrict__ w1,
    const float* __restrict__ w2, const float* __restrict__ w3,
    const float* __restrict__ w4,
    unsigned short* __restrict__ t0, unsigned short* __restrict__ t1,
    unsigned short* __restrict__ t2, unsigned short* __restrict__ t3,
    unsigned short* __restrict__ t4)
{
    int idx = blockIdx.x * 256 + threadIdx.x;
    int y = blockIdx.y;
    if (y < 4) {
        const float* w = y == 0 ? w0 : y == 1 ? w1 : y == 2 ? w2 : w3;
        unsigned short* t = y == 0 ? t0 : y == 1 ? t1 : y == 2 ? t2 : t3;
        wtrans_one(w, t, 128, 128, idx);
    } else {
        if (idx < 9 * 4 * 80 * 32) wtrans_one(w4, t4, 72, 80, idx);
    }
}

// ---- SE FC + per-batch scaled weight copy, fused ---------------------------
__global__ __launch_bounds__(256) void wscale8f(
    const unsigned short* __restrict__ wT, const float* __restrict__ meanb,
    const float* __restrict__ w1, const float* __restrict__ b1,
    const float* __restrict__ w2, const float* __restrict__ b2,
    unsigned short* __restrict__ out, int Coutp)
{
    const int b = blockIdx.y, c = threadIdx.x;
    __shared__ float h1[8];
    __shared__ float sl[128];
    if (c < 8) {
        float s = 0.f;
        for (int j = 0; j < 128; ++j) s += w1[c * 128 + j] * meanb[b * 128 + j];
        h1[c] = fmaxf(s * (1.f / 16384.f) + b1[c], 0.f);
    }
    __syncthreads();
    if (c < 128) {
        float s = b2[c];
        #pragma unroll
        for (int j = 0; j < 8; ++j) s += w2[c * 8 + j] * h1[j];
        sl[c] = 1.f / (1.f + expf(-s));
    }
    __syncthreads();
    int r = blockIdx.x * 256 + c;
    int ch = r & 31;
    int kc = ((r >> 5) / Coutp) & 3;
    out[(size_t)b * (9 * 4 * Coutp * 32) + r] = f2bf(bf2f(wT[r]) * sl[kc * 32 + ch]);
}

// ---------------------------------------------------------------------------
extern "C" void kernel_launch(void* const* d_in, const int* in_sizes, int n_in,
                              void* d_out, int out_size, void* d_ws, size_t ws_size,
                              hipStream_t stream)
{
    const float* x      = (const float*)d_in[0];
    const float* w_head = (const float*)d_in[1];
    const float* b_head = (const float*)d_in[2];
    const float* w_h1a  = (const float*)d_in[3];
    const float* b_h1a  = (const float*)d_in[4];
    const float* w_h1b  = (const float*)d_in[5];
    const float* b_h1b  = (const float*)d_in[6];
    const float* du1_w1 = (const float*)d_in[7];
    const float* du1_b1 = (const float*)d_in[8];
    const float* du1_w2 = (const float*)d_in[9];
    const float* du1_b2 = (const float*)d_in[10];
    const float* w_h2a  = (const float*)d_in[11];
    const float* b_h2a  = (const float*)d_in[12];
    const float* w_h2b  = (const float*)d_in[13];
    const float* b_h2b  = (const float*)d_in[14];
    const float* du2_w1 = (const float*)d_in[15];
    const float* du2_b1 = (const float*)d_in[16];
    const float* du2_w2 = (const float*)d_in[17];
    const float* du2_b2 = (const float*)d_in[18];
    const float* w_tail = (const float*)d_in[19];
    const float* b_tail = (const float*)d_in[20];
    const float* kern   = (const float*)d_in[21];
    float* out = (float*)d_out;

    unsigned short* fb0  = (unsigned short*)d_ws;        // 16,777,216 elems
    unsigned short* fb1  = fb0 + 16777216;
    unsigned short* wt1  = fb1 + 16777216;               // 9*4*128*32 = 147456 each
    unsigned short* wt2  = wt1 + 147456;
    unsigned short* wt3  = wt2 + 147456;
    unsigned short* wt4  = wt3 + 147456;
    unsigned short* wtt  = wt4 + 147456;                 // 9*4*80*32 = 92160
    unsigned short* wsa  = wtt + 92160;                  // 8x scaled h2a weights
    unsigned short* wst  = wsa + 8 * 147456;             // 8x scaled tail weights
    float* mean1  = (float*)(wst + 8 * 92160);           // 1024
    float* mean2  = mean1 + 1024;

    dim3 blk(256);
    hipMemsetAsync(mean1, 0, 8192, stream);              // zero mean1+mean2

    wtrans5<<<dim3(576, 5), blk, 0, stream>>>(w_h1a, w_h1b, w_h2a, w_h2b, w_tail,
                                              wt1, wt2, wt3, wt4, wtt);

    head_conv<<<dim3(16, 16, 8), blk, 0, stream>>>(x, w_head, b_head, fb0);

    dim3 cgrid(64, 8);   // 512 blocks: 64 tiles/batch x 8 batches
    conv_mfma<8, 4, 1, 0, 0><<<cgrid, blk, 0, stream>>>(
        fb0, wt1, 0, b_h1a, fb1, nullptr, nullptr, nullptr, nullptr, 128, 128, 1);
    conv_mfma<8, 4, 1, 1, 0><<<cgrid, blk, 0, stream>>>(
        fb1, wt2, 0, b_h1b, fb0, mean1, nullptr, nullptr, nullptr, 128, 128, 1);

    wscale8f<<<dim3(576, 8), blk, 0, stream>>>(wt3, mean1, du1_w1, du1_b1,
                                               du1_w2, du1_b2, wsa, 128);

    conv_mfma<8, 4, 1, 0, 0><<<cgrid, blk, 0, stream>>>(
        fb0, wsa, 147456, b_h2a, fb1, nullptr, nullptr, nullptr, nullptr, 128, 128, 1);
    conv_mfma<8, 4, 1, 1, 0><<<cgrid, blk, 0, stream>>>(
        fb1, wt4, 0, b_h2b, fb0, mean2, nullptr, nullptr, nullptr, 128, 128, 1);

    wscale8f<<<dim3(360, 8), blk, 0, stream>>>(wtt, mean2, du2_w1, du2_b1,
                                               du2_w2, du2_b2, wst, 80);

    // tail conv + fused dynamic filter (writes final output directly)
    conv_mfma<4, 5, 0, 0, 1><<<cgrid, blk, 0, stream>>>(
        fb0, wst, 92160, b_tail, nullptr, nullptr, x, kern, out, 80, 72, 0);
}

// Round 10
// 341.037 us; speedup vs baseline: 1.4019x; 1.0537x over previous
//
#include <hip/hip_runtime.h>
#include <math.h>

// ---------------------------------------------------------------------------
// R10: tail epilogue e-build (e[px][25] = sum_co wgt[px][co]*kern[co][i])
// converted from 1800 scalar VALU FMAs/thread to a chained MFMA GEMM
// (P through LDS, kern prepacked to B-frag layout bf16). Rest identical R9.
// ---------------------------------------------------------------------------

typedef __attribute__((ext_vector_type(8))) short bf16x8;
typedef __attribute__((ext_vector_type(4))) float f32x4;

__device__ inline float bf2f(unsigned short u) {
    unsigned v = ((unsigned)u) << 16;
    return __builtin_bit_cast(float, v);
}
__device__ inline unsigned short f2bf(float f) {
    unsigned u = __builtin_bit_cast(unsigned, f);
    u += 0x7FFF + ((u >> 16) & 1);   // RNE
    return (unsigned short)(u >> 16);
}

// ---------------- head conv: fp32 NCHW (Cin=3) -> NHWC bf16 (C=128) ---------
__global__ __launch_bounds__(256) void head_conv(
    const float* __restrict__ x, const float* __restrict__ w,
    const float* __restrict__ bias, unsigned short* __restrict__ out)
{
    __shared__ float wlds[216];          // [ci][tap][co8]
    __shared__ float tile[3][34 * 34];
    const int tid = threadIdx.x, cog = blockIdx.y, b = blockIdx.z;
    const int tile_y = (blockIdx.x >> 2) * 32, tile_x = (blockIdx.x & 3) * 32;

    if (tid < 216) {
        int co = tid & 7, rest = tid >> 3, tap = rest % 9, ci = rest / 9;
        wlds[tid] = w[((cog * 8 + co) * 3 + ci) * 9 + tap];
    }
    for (int idx = tid; idx < 3 * 34 * 34; idx += 256) {
        int ci = idx / 1156, rem = idx - ci * 1156;
        int r = rem / 34, c = rem - r * 34;
        int gy = tile_y - 1 + r, gx = tile_x - 1 + c;
        float v = 0.f;
        if ((unsigned)gy < 128u && (unsigned)gx < 128u)
            v = x[(((size_t)(b * 3 + ci)) << 14) + (gy << 7) + gx];
        tile[ci][rem] = v;
    }
    __syncthreads();

    const int ty = tid >> 4, tx = tid & 15, py = ty * 2;
    float acc[2][2][8];
    #pragma unroll
    for (int r = 0; r < 2; ++r)
        #pragma unroll
        for (int h = 0; h < 2; ++h)
            #pragma unroll
            for (int co = 0; co < 8; ++co) acc[r][h][co] = 0.f;

    #pragma unroll
    for (int ci = 0; ci < 3; ++ci) {
        #pragma unroll
        for (int ky = 0; ky < 3; ++ky) {
            #pragma unroll
            for (int kx = 0; kx < 3; ++kx) {
                const float* wp = wlds + (ci * 9 + ky * 3 + kx) * 8;
                float i00 = tile[ci][(py + ky) * 34 + tx + kx];
                float i01 = tile[ci][(py + ky) * 34 + tx + 16 + kx];
                float i10 = tile[ci][(py + 1 + ky) * 34 + tx + kx];
                float i11 = tile[ci][(py + 1 + ky) * 34 + tx + 16 + kx];
                #pragma unroll
                for (int co = 0; co < 8; ++co) {
                    float wv = wp[co];
                    acc[0][0][co] += i00 * wv;
                    acc[0][1][co] += i01 * wv;
                    acc[1][0][co] += i10 * wv;
                    acc[1][1][co] += i11 * wv;
                }
            }
        }
    }

    #pragma unroll
    for (int r = 0; r < 2; ++r) {
        #pragma unroll
        for (int h = 0; h < 2; ++h) {
            int gy = tile_y + py + r, gx = tile_x + tx + h * 16;
            bf16x8 pv;
            #pragma unroll
            for (int co = 0; co < 8; ++co)
                pv[co] = (short)f2bf(acc[r][h][co] + bias[cog * 8 + co]);
            *(bf16x8*)(out + (((((size_t)b << 14) + gy * 128 + gx)) << 7) + cog * 8) = pv;
        }
    }
}

// ---------------- main conv: implicit GEMM, bf16 MFMA -----------------------
// Block: 16x16 px tile; A staged in two 64-ch halves, UNPADDED stride 64 ush
// with XOR swizzle (channel-group p = g ^ (px&7)) -> conflict-free b128 reads.
// WNSPLIT=1: 4 waves tile 2 m-groups x 2 n-groups (LM=8, NTW=4 for 128 co).
// DOMEAN: fused SE pooled-sum. TAILFUSE: dynfilter fused (MFMA e-GEMM).
template <int LM, int NTW, int WNSPLIT, int DOMEAN, int TAILFUSE>
__global__ __launch_bounds__(256, 2) void conv_mfma(
    const unsigned short* __restrict__ in, const unsigned short* __restrict__ wT,
    size_t wstride, const float* __restrict__ bias, unsigned short* __restrict__ out,
    float* __restrict__ meanb, const float* __restrict__ x,
    const unsigned short* __restrict__ kb, float* __restrict__ outf,
    int Coutp, int Cout, int relu)
{
    __shared__ unsigned short lds[TAILFUSE ? 256 * 104 : 324 * 64];
    const int tid = threadIdx.x;
    const int b = blockIdx.y;
    const int row0 = (blockIdx.x >> 3) << 4;
    const int col0 = (blockIdx.x & 7) << 4;
    const int l = tid & 63, wv = tid >> 6;
    const int li = l & 15, lq = l >> 4;
    const int m_base = WNSPLIT ? (wv >> 1) * LM : wv * LM;
    const int n_base = WNSPLIT ? (wv & 1) * NTW : 0;
    const size_t inb = ((size_t)b) << 14;
    const unsigned short* wbase = wT + (size_t)b * wstride;

    f32x4 acc[LM][NTW];
    #pragma unroll
    for (int lm = 0; lm < LM; ++lm)
        #pragma unroll
        for (int nt = 0; nt < NTW; ++nt)
            acc[lm][nt] = (f32x4){0.f, 0.f, 0.f, 0.f};

    #pragma unroll 1
    for (int half = 0; half < 2; ++half) {
        __syncthreads();
        for (int u = tid; u < 2592; u += 256) {   // 324 px * 8 ch-groups
            int px = u >> 3, g = u & 7;
            int hr = px / 18, hc = px - hr * 18;
            int gy = row0 - 1 + hr, gx = col0 - 1 + hc;
            bf16x8 v = {0, 0, 0, 0, 0, 0, 0, 0};
            if ((unsigned)gy < 128u && (unsigned)gx < 128u)
                v = *(const bf16x8*)(in + ((inb + (gy << 7) + gx) << 7) + half * 64 + g * 8);
            int p = g ^ (px & 7);                 // XOR swizzle
            *(bf16x8*)(lds + px * 64 + p * 8) = v;
        }
        __syncthreads();

        auto loadB = [&](bf16x8 (&dst)[NTW], int s) {
            int tap = s >> 1, kcl = s & 1;
            const unsigned short* p = wbase +
                (size_t)(tap * 4 + half * 2 + kcl) * (Coutp * 32) +
                (n_base * 16 + li) * 32 + lq * 8;
            #pragma unroll
            for (int nt = 0; nt < NTW; ++nt)
                dst[nt] = *(const bf16x8*)(p + nt * 512);
        };
        auto compute = [&](bf16x8 (&bf)[NTW], int s) {
            int tap = s >> 1, kcl = s & 1;
            int ky = tap / 3, kx = tap - ky * 3;
            int g = kcl * 4 + lq;
            #pragma unroll
            for (int lm = 0; lm < LM; ++lm) {
                int px = (m_base + lm + ky) * 18 + li + kx;
                bf16x8 af = *(const bf16x8*)(lds + px * 64 + ((g ^ (px & 7)) * 8));
                #pragma unroll
                for (int nt = 0; nt < NTW; ++nt)
                    acc[lm][nt] = __builtin_amdgcn_mfma_f32_16x16x32_bf16(
                        af, bf[nt], acc[lm][nt], 0, 0, 0);
            }
        };

        bf16x8 bufA[NTW], bufB[NTW];
        loadB(bufA, 0);
        #pragma unroll 1
        for (int it = 0; it < 18; it += 2) {
            loadB(bufB, it + 1);
            compute(bufA, it);
            if (it + 2 < 18) loadB(bufA, it + 2);
            compute(bufB, it + 1);
        }
    }

    float bv[NTW], msum[NTW];
    #pragma unroll
    for (int nt = 0; nt < NTW; ++nt) {
        int co = (n_base + nt) * 16 + li;
        bv[nt] = (co < Cout) ? bias[co] : 0.f;
        msum[nt] = 0.f;
    }

    if (TAILFUSE) {
        // ---- P (wgt) -> LDS, stride 104 ush; zero pad co 80..95 ----
        __syncthreads();   // conv af-region dead, reuse LDS
        #pragma unroll
        for (int lm = 0; lm < LM; ++lm) {
            int rowl = m_base + lm;
            #pragma unroll
            for (int r = 0; r < 4; ++r) {
                int coll = lq * 4 + r;
                #pragma unroll
                for (int nt = 0; nt < NTW; ++nt)
                    lds[(rowl * 16 + coll) * 104 + nt * 16 + li] =
                        f2bf(acc[lm][nt][r] + bv[nt]);
            }
        }
        {
            bf16x8 z = {0, 0, 0, 0, 0, 0, 0, 0};
            *(bf16x8*)(lds + tid * 104 + 80) = z;
            *(bf16x8*)(lds + tid * 104 + 88) = z;
        }
        __syncthreads();

        // ---- e-GEMM: e[px][i] = sum_co P[px][co] * kern[co][i] ----
        // M=256 px (16 m-tiles, 4/wave), N=32 (2 n-tiles, i<25 valid),
        // K=96 (3 slices of 32; kb zero-padded co>=72).
        f32x4 eacc[4][2];
        #pragma unroll
        for (int mm = 0; mm < 4; ++mm)
            #pragma unroll
            for (int nt = 0; nt < 2; ++nt)
                eacc[mm][nt] = (f32x4){0.f, 0.f, 0.f, 0.f};
        #pragma unroll
        for (int s = 0; s < 3; ++s) {
            bf16x8 kbf[2];
            #pragma unroll
            for (int nt = 0; nt < 2; ++nt)
                kbf[nt] = *(const bf16x8*)(kb + ((s * 2 + nt) * 16 + li) * 32 + lq * 8);
            #pragma unroll
            for (int mm = 0; mm < 4; ++mm) {
                int px = (wv * 4 + mm) * 16 + li;
                bf16x8 pf = *(const bf16x8*)(lds + px * 104 + s * 32 + lq * 8);
                #pragma unroll
                for (int nt = 0; nt < 2; ++nt)
                    eacc[mm][nt] = __builtin_amdgcn_mfma_f32_16x16x32_bf16(
                        pf, kbf[nt], eacc[mm][nt], 0, 0, 0);
            }
        }
        __syncthreads();

        // ---- e (C-layout) -> LDS fp32, stride 33 ----
        float* elds = (float*)lds;
        #pragma unroll
        for (int mm = 0; mm < 4; ++mm) {
            #pragma unroll
            for (int nt = 0; nt < 2; ++nt) {
                int i = nt * 16 + li;
                if (i < 25) {
                    #pragma unroll
                    for (int r = 0; r < 4; ++r) {
                        int px = (wv * 4 + mm) * 16 + lq * 4 + r;
                        elds[px * 33 + i] = eacc[mm][nt][r];
                    }
                }
            }
        }
        __syncthreads();

        // ---- apply: out[b,c,h,w] = sum_{dy,dx} e[dy*5+dx] * x_reflect ----
        const int h = row0 + (tid >> 4), w = col0 + (tid & 15);
        const int pix = h * 128 + w;
        float e[25];
        #pragma unroll
        for (int i = 0; i < 25; ++i) e[i] = elds[tid * 33 + i];

        int yy[5], xx[5];
        #pragma unroll
        for (int d = 0; d < 5; ++d) {
            int y = h - 2 + d;
            yy[d] = y < 0 ? -y : (y > 127 ? 254 - y : y);
            int xv = w - 2 + d;
            xx[d] = xv < 0 ? -xv : (xv > 127 ? 254 - xv : xv);
        }
        #pragma unroll
        for (int c = 0; c < 3; ++c) {
            const float* xc = x + ((size_t)(b * 3 + c) << 14);
            float s = 0.f;
            #pragma unroll
            for (int dy = 0; dy < 5; ++dy)
                #pragma unroll
                for (int dx = 0; dx < 5; ++dx)
                    s += e[dy * 5 + dx] * xc[yy[dy] * 128 + xx[dx]];
            outf[((size_t)(b * 3 + c) << 14) + pix] = s;
        }
        return;
    }

    #pragma unroll
    for (int lm = 0; lm < LM; ++lm) {
        int row = row0 + m_base + lm;
        #pragma unroll
        for (int r = 0; r < 4; ++r) {
            int col = col0 + lq * 4 + r;
            size_t pbase = (inb + row * 128 + col) * (size_t)Coutp;
            #pragma unroll
            for (int nt = 0; nt < NTW; ++nt) {
                float v = acc[lm][nt][r] + bv[nt];
                if (relu) v = fmaxf(v, 0.f);
                if (DOMEAN) msum[nt] += v;
                out[pbase + (n_base + nt) * 16 + li] = f2bf(v);
            }
        }
    }
    if (DOMEAN) {
        #pragma unroll
        for (int nt = 0; nt < NTW; ++nt) {
            float t = msum[nt];
            t += __shfl_xor(t, 16, 64);
            t += __shfl_xor(t, 32, 64);
            if (lq == 0)
                atomicAdd(&meanb[b * 128 + (n_base + nt) * 16 + li], t);
        }
    }
}

// ---- weight transform: [Co][128][3][3] f32 -> [tap*4+kc][Coutp][32] bf16 ---
__device__ inline void wtrans_one(const float* w, unsigned short* wT,
                                  int Co, int Coutp, int idx)
{
    int ch = idx & 31;
    int rest = idx >> 5;
    int co = rest % Coutp;
    int slice = rest / Coutp;
    int kc = slice & 3, tap = slice >> 2;
    float v = (co < Co) ? w[((size_t)(co * 128 + kc * 32 + ch)) * 9 + tap] : 0.f;
    wT[idx] = f2bf(v);
}

__global__ __launch_bounds__(256) void wtrans6(
    const float* __restrict__ w0, const float* __restrict__ w1,
    const float* __restrict__ w2, const float* __restrict__ w3,
    const float* __restrict__ w4, const float* __restrict__ kern,
    unsigned short* __restrict__ t0, unsigned short* __restrict__ t1,
    unsigned short* __restrict__ t2, unsigned short* __restrict__ t3,
    unsigned short* __restrict__ t4, unsigned short* __restrict__ kb)
{
    int idx = blockIdx.x * 256 + threadIdx.x;
    int y = blockIdx.y;
    if (y < 4) {
        const float* w = y == 0 ? w0 : y == 1 ? w1 : y == 2 ? w2 : w3;
        unsigned short* t = y == 0 ? t0 : y == 1 ? t1 : y == 2 ? t2 : t3;
        wtrans_one(w, t, 128, 128, idx);
    } else if (y == 4) {
        if (idx < 9 * 4 * 80 * 32) wtrans_one(w4, t4, 72, 80, idx);
    } else {
        // kb[((s*2+nt)*16+li)*32 + lq*8 + j] = kern[co=s*32+lq*8+j][i=nt*16+li]
        if (idx < 3072) {
            int lq = (idx & 31) >> 3, j = idx & 7;
            int row = idx >> 5;
            int li = row & 15, snt = row >> 4;
            int s = snt >> 1, nt = snt & 1;
            int co = s * 32 + lq * 8 + j, i = nt * 16 + li;
            float v = (co < 72 && i < 25) ? kern[co * 25 + i] : 0.f;
            kb[idx] = f2bf(v);
        }
    }
}

// ---- SE FC + per-batch scaled weight copy, fused ---------------------------
__global__ __launch_bounds__(256) void wscale8f(
    const unsigned short* __restrict__ wT, const float* __restrict__ meanb,
    const float* __restrict__ w1, const float* __restrict__ b1,
    const float* __restrict__ w2, const float* __restrict__ b2,
    unsigned short* __restrict__ out, int Coutp)
{
    const int b = blockIdx.y, c = threadIdx.x;
    __shared__ float h1[8];
    __shared__ float sl[128];
    if (c < 8) {
        float s = 0.f;
        for (int j = 0; j < 128; ++j) s += w1[c * 128 + j] * meanb[b * 128 + j];
        h1[c] = fmaxf(s * (1.f / 16384.f) + b1[c], 0.f);
    }
    __syncthreads();
    if (c < 128) {
        float s = b2[c];
        #pragma unroll
        for (int j = 0; j < 8; ++j) s += w2[c * 8 + j] * h1[j];
        sl[c] = 1.f / (1.f + expf(-s));
    }
    __syncthreads();
    int r = blockIdx.x * 256 + c;
    int ch = r & 31;
    int kc = ((r >> 5) / Coutp) & 3;
    out[(size_t)b * (9 * 4 * Coutp * 32) + r] = f2bf(bf2f(wT[r]) * sl[kc * 32 + ch]);
}

// ---------------------------------------------------------------------------
extern "C" void kernel_launch(void* const* d_in, const int* in_sizes, int n_in,
                              void* d_out, int out_size, void* d_ws, size_t ws_size,
                              hipStream_t stream)
{
    const float* x      = (const float*)d_in[0];
    const float* w_head = (const float*)d_in[1];
    const float* b_head = (const float*)d_in[2];
    const float* w_h1a  = (const float*)d_in[3];
    const float* b_h1a  = (const float*)d_in[4];
    const float* w_h1b  = (const float*)d_in[5];
    const float* b_h1b  = (const float*)d_in[6];
    const float* du1_w1 = (const float*)d_in[7];
    const float* du1_b1 = (const float*)d_in[8];
    const float* du1_w2 = (const float*)d_in[9];
    const float* du1_b2 = (const float*)d_in[10];
    const float* w_h2a  = (const float*)d_in[11];
    const float* b_h2a  = (const float*)d_in[12];
    const float* w_h2b  = (const float*)d_in[13];
    const float* b_h2b  = (const float*)d_in[14];
    const float* du2_w1 = (const float*)d_in[15];
    const float* du2_b1 = (const float*)d_in[16];
    const float* du2_w2 = (const float*)d_in[17];
    const float* du2_b2 = (const float*)d_in[18];
    const float* w_tail = (const float*)d_in[19];
    const float* b_tail = (const float*)d_in[20];
    const float* kern   = (const float*)d_in[21];
    float* out = (float*)d_out;

    unsigned short* fb0  = (unsigned short*)d_ws;        // 16,777,216 elems
    unsigned short* fb1  = fb0 + 16777216;
    unsigned short* wt1  = fb1 + 16777216;               // 9*4*128*32 = 147456 each
    unsigned short* wt2  = wt1 + 147456;
    unsigned short* wt3  = wt2 + 147456;
    unsigned short* wt4  = wt3 + 147456;
    unsigned short* wtt  = wt4 + 147456;                 // 9*4*80*32 = 92160
    unsigned short* wsa  = wtt + 92160;                  // 8x scaled h2a weights
    unsigned short* wst  = wsa + 8 * 147456;             // 8x scaled tail weights
    unsigned short* kbb  = wst + 8 * 92160;              // 3072 (kern B-frag)
    float* mean1  = (float*)(kbb + 3072);                // 1024
    float* mean2  = mean1 + 1024;

    dim3 blk(256);
    hipMemsetAsync(mean1, 0, 8192, stream);              // zero mean1+mean2

    wtrans6<<<dim3(576, 6), blk, 0, stream>>>(w_h1a, w_h1b, w_h2a, w_h2b, w_tail,
                                              kern, wt1, wt2, wt3, wt4, wtt, kbb);

    head_conv<<<dim3(16, 16, 8), blk, 0, stream>>>(x, w_head, b_head, fb0);

    dim3 cgrid(64, 8);   // 512 blocks: 64 tiles/batch x 8 batches
    conv_mfma<8, 4, 1, 0, 0><<<cgrid, blk, 0, stream>>>(
        fb0, wt1, 0, b_h1a, fb1, nullptr, nullptr, nullptr, nullptr, 128, 128, 1);
    conv_mfma<8, 4, 1, 1, 0><<<cgrid, blk, 0, stream>>>(
        fb1, wt2, 0, b_h1b, fb0, mean1, nullptr, nullptr, nullptr, 128, 128, 1);

    wscale8f<<<dim3(576, 8), blk, 0, stream>>>(wt3, mean1, du1_w1, du1_b1,
                                               du1_w2, du1_b2, wsa, 128);

    conv_mfma<8, 4, 1, 0, 0><<<cgrid, blk, 0, stream>>>(
        fb0, wsa, 147456, b_h2a, fb1, nullptr, nullptr, nullptr, nullptr, 128, 128, 1);
    conv_mfma<8, 4, 1, 1, 0><<<cgrid, blk, 0, stream>>>(
        fb1, wt4, 0, b_h2b, fb0, mean2, nullptr, nullptr, nullptr, 128, 128, 1);

    wscale8f<<<dim3(360, 8), blk, 0, stream>>>(wtt, mean2, du2_w1, du2_b1,
                                               du2_w2, du2_b2, wst, 80);

    // tail conv + fused dynamic filter via MFMA e-GEMM (writes final output)
    conv_mfma<4, 5, 0, 0, 1><<<cgrid, blk, 0, stream>>>(
        fb0, wst, 92160, b_tail, nullptr, nullptr, x, kbb, out, 80, 72, 0);
}